// Round 5
// baseline (245.044 us; speedup 1.0000x reference)
//
#include <hip/hip_runtime.h>
#include <math.h>

#define BB 4
#define DL 150
#define PL 1000
#define CD 64
#define NC1 40
#define NC2 80
#define NC3 160
#define L1O 997
#define L2O 990
#define L3O 979
#define L1P 1000
#define L2P 992
#define L3P 980
#define DLP 152
#define PLP 984
#define NINF (-1e30f)

__device__ __forceinline__ float relu_(float x){ return fmaxf(x, 0.f); }
__device__ __forceinline__ float lrelu_(float x){ return x > 0.f ? x : 0.01f * x; }

__device__ __forceinline__ unsigned fenc(float x){
  unsigned u = __float_as_uint(x);
  return (u & 0x80000000u) ? ~u : (u | 0x80000000u);
}
__device__ __forceinline__ float fdec(unsigned u){
  return __uint_as_float((u & 0x80000000u) ? (u & 0x7fffffffu) : ~u);
}
__device__ __forceinline__ float4 relu4_(float4 v){
  v.x = fmaxf(v.x, 0.f); v.y = fmaxf(v.y, 0.f);
  v.z = fmaxf(v.z, 0.f); v.w = fmaxf(v.w, 0.f);
  return v;
}

// ---- proj table: proj[tok][k][co] = sum_ci emb[tok][ci] * w1[co][ci][k] ----
__global__ void k_proj(const float* __restrict__ emb, const float* __restrict__ w1,
                       float* __restrict__ projG){
  int e = blockIdx.x * 256 + threadIdx.x;
  if (e >= 26 * 160) return;
  int tok = e / 160, rem = e % 160, k = rem / 40, co = rem % 40;
  float a = 0.f;
  const float* er = emb + tok * CD;
  const float* wr = w1 + co * (CD * 4) + k;
  #pragma unroll 8
  for (int ci = 0; ci < CD; ci++) a = fmaf(er[ci], wr[ci * 4], a);
  projG[tok * 161 + k * 40 + co] = a;
}

// ---- conv1 apply (writes relu'd h1) ----
__global__ __launch_bounds__(256) void k_conv1(const int* __restrict__ prot,
                        const float* __restrict__ projG, const float* __restrict__ b1,
                        float* __restrict__ h1){
  __shared__ float sp[26 * 161];
  int b = blockIdx.x / 80;
  int t = (blockIdx.x % 80) * 256 + threadIdx.x;
  for (int k = threadIdx.x; k < 26 * 161; k += 256) sp[k] = projG[k];
  __syncthreads();
  int p = t & 1023, co2 = t >> 10;
  if (p >= L1O) return;
  const int* pr = prot + b * PL + p;
  int t0 = pr[0], t1 = pr[1], t2 = pr[2], t3 = pr[3];
  #pragma unroll
  for (int c = 0; c < 2; c++){
    int co = co2 * 2 + c;
    float a = b1[co] + sp[t0 * 161 + co] + sp[t1 * 161 + 40 + co]
            + sp[t2 * 161 + 80 + co] + sp[t3 * 161 + 120 + co];
    h1[(size_t)(b * NC1 + co) * L1P + p] = relu_(a);
  }
}

// ---- conv2 split-K: grid 640 = b(4) x cog(5,16co) x pt(16,64p) x half(2,20ci) ----
// 128 threads, 8 outputs/thread (1co x 8p). Pre-relu partial sums atomicAdd'd to h2.
__global__ __launch_bounds__(128) void k_conv2s(const float* __restrict__ x,
                        const float* __restrict__ w, const float* __restrict__ bias,
                        float* __restrict__ h2){
  __shared__ float xs[20 * 76];               // 6.1 KB
  __shared__ float wl[16 * 164];              // 10.5 KB
  int blk = blockIdx.x;
  int half = blk & 1; int t = blk >> 1;
  int pt = t & 15; t >>= 4;
  int cog = t % 5; int b = t / 5;
  int co0 = cog * 16, pblk = pt * 64, ci0 = half * 20;
  int tid = threadIdx.x;
  const float* xb = x + ((size_t)(b * NC1 + ci0)) * L1P + pblk;
  for (int i = tid; i < 380; i += 128){       // 20 rows x 19 f4
    int r = i / 19, c = i % 19;
    *(float4*)(&xs[r * 76 + c * 4]) = *(const float4*)(xb + (size_t)r * L1P + c * 4);
  }
  for (int i = tid; i < 640; i += 128){       // 16 co x 40 f4
    int cc = i / 40, c = i % 40;
    *(float4*)(&wl[cc * 164 + c * 4]) =
        *(const float4*)(w + (size_t)(co0 + cc) * 320 + ci0 * 8 + c * 4);
  }
  __syncthreads();
  int co_l = tid >> 3, pg = tid & 7, p0 = pg * 8;
  float acc[8] = {0,0,0,0,0,0,0,0};
  const float* wc = &wl[co_l * 164];
  #pragma unroll 2
  for (int ci = 0; ci < 20; ci++){
    const float* xrow = &xs[ci * 76 + p0];
    float xv[16];
    *(float4*)(&xv[0])  = *(const float4*)(xrow);
    *(float4*)(&xv[4])  = *(const float4*)(xrow + 4);
    *(float4*)(&xv[8])  = *(const float4*)(xrow + 8);
    *(float4*)(&xv[12]) = *(const float4*)(xrow + 12);
    float wk[8];
    *(float4*)(&wk[0]) = *(const float4*)(wc + ci * 8);
    *(float4*)(&wk[4]) = *(const float4*)(wc + ci * 8 + 4);
    #pragma unroll
    for (int k = 0; k < 8; k++){
      #pragma unroll
      for (int pp = 0; pp < 8; pp++)
        acc[pp] = fmaf(xv[pp + k], wk[k], acc[pp]);
    }
  }
  int co = co0 + co_l;
  float bv = (half == 0) ? bias[co] : 0.f;
  float* yr = h2 + (size_t)(b * NC2 + co) * L2P;
  int pbase = pblk + p0;
  #pragma unroll
  for (int pp = 0; pp < 8; pp++){
    int p = pbase + pp;
    if (p < L2O) atomicAdd(&yr[p], acc[pp] + bv);
  }
}

// ---- conv3 split-K: grid 1280 = b(4) x cog(10,16co) x pt(16,64p) x half(2,40ci) ----
// X staged with relu (h2 is pre-relu). Partial sums atomicAdd'd into pconv (pre-relu).
__global__ __launch_bounds__(128) void k_conv3s(const float* __restrict__ h2,
                        const float* __restrict__ w, const float* __restrict__ bias,
                        float* __restrict__ pconv){
  __shared__ float xs[40 * 76];               // 12.2 KB
  __shared__ float wl[16 * 484];              // 31.0 KB
  int blk = blockIdx.x;
  int half = blk & 1; int t = blk >> 1;
  int pt = t & 15; t >>= 4;
  int cog = t % 10; int b = t / 10;
  int co0 = cog * 16, pblk = pt * 64, ci0 = half * 40;
  int tid = threadIdx.x;
  const float* xb = h2 + ((size_t)(b * NC2 + ci0)) * L2P + pblk;
  for (int i = tid; i < 760; i += 128){       // 40 rows x 19 f4, relu at stage
    int r = i / 19, c = i % 19;
    float4 v = *(const float4*)(xb + (size_t)r * L2P + c * 4);
    *(float4*)(&xs[r * 76 + c * 4]) = relu4_(v);
  }
  for (int i = tid; i < 1920; i += 128){      // 16 co x 120 f4
    int cc = i / 120, c = i % 120;
    *(float4*)(&wl[cc * 484 + c * 4]) =
        *(const float4*)(w + (size_t)(co0 + cc) * 960 + ci0 * 12 + c * 4);
  }
  __syncthreads();
  int co_l = tid >> 3, pg = tid & 7, p0 = pg * 8;
  float acc[8] = {0,0,0,0,0,0,0,0};
  const float* wc = &wl[co_l * 484];
  #pragma unroll 2
  for (int ci = 0; ci < 40; ci++){
    const float* xrow = &xs[ci * 76 + p0];
    float xv[20];
    *(float4*)(&xv[0])  = *(const float4*)(xrow);
    *(float4*)(&xv[4])  = *(const float4*)(xrow + 4);
    *(float4*)(&xv[8])  = *(const float4*)(xrow + 8);
    *(float4*)(&xv[12]) = *(const float4*)(xrow + 12);
    *(float4*)(&xv[16]) = *(const float4*)(xrow + 16);
    float wk[12];
    *(float4*)(&wk[0]) = *(const float4*)(wc + ci * 12);
    *(float4*)(&wk[4]) = *(const float4*)(wc + ci * 12 + 4);
    *(float4*)(&wk[8]) = *(const float4*)(wc + ci * 12 + 8);
    #pragma unroll
    for (int k = 0; k < 12; k++){
      #pragma unroll
      for (int pp = 0; pp < 8; pp++)
        acc[pp] = fmaf(xv[pp + k], wk[k], acc[pp]);
    }
  }
  int co = co0 + co_l;
  float bv = (half == 0) ? bias[co] : 0.f;
  float* yr = pconv + (size_t)(b * NC3 + co) * L3P;
  int pbase = pblk + p0;
  #pragma unroll
  for (int pp = 0; pp < 8; pp++){
    int p = pbase + pp;
    if (p < L3O) atomicAdd(&yr[p], acc[pp] + bv);
  }
}

// ---- drug attention (80 blocks x 256) + enc init ----
__global__ __launch_bounds__(256) void k_datt(const float* __restrict__ drug,
                        const int* __restrict__ natoms,
                        const float* __restrict__ Wd, const float* __restrict__ bd,
                        float* __restrict__ dattT, unsigned* __restrict__ enc){
  int blk = blockIdx.x;
  if (blk == 0){
    for (int k = threadIdx.x; k < 2 * BB * NC3; k += 256) enc[k] = 0u;
  }
  int b = blk / 20, c0 = (blk % 20) * 8;
  int i = threadIdx.x;
  if (i >= DL) return;
  const float4* xr = (const float4*)(drug + ((size_t)b * DL + i) * NC3);
  float4 a[8];
  #pragma unroll
  for (int cc = 0; cc < 8; cc++) a[cc] = make_float4(0.f, 0.f, 0.f, 0.f);
  for (int k4 = 0; k4 < 40; k4++){
    float4 xv = xr[k4];
    #pragma unroll
    for (int cc = 0; cc < 8; cc++){
      float4 wv = ((const float4*)(Wd + (size_t)(c0 + cc) * NC3))[k4];
      a[cc].x = fmaf(xv.x, wv.x, a[cc].x);
      a[cc].y = fmaf(xv.y, wv.y, a[cc].y);
      a[cc].z = fmaf(xv.z, wv.z, a[cc].z);
      a[cc].w = fmaf(xv.w, wv.w, a[cc].w);
    }
  }
  bool act = i < natoms[b];
  #pragma unroll
  for (int cc = 0; cc < 8; cc++){
    float r = act ? (a[cc].x + a[cc].y + a[cc].z + a[cc].w + bd[c0 + cc]) : 0.f;
    dattT[(size_t)(b * NC3 + c0 + cc) * DLP + i] = r;
  }
}

// ---- protein attention, tiled GEMM: grid 640 = b(4) x cog(10,16co) x jt(16,64j) ----
// 128 threads, out/thread = 2co x 4j. X = relu(pconv) staged whole-K.
__global__ __launch_bounds__(128) void k_patt(const float* __restrict__ pconv,
                        const int* __restrict__ prot,
                        const float* __restrict__ Wp, const float* __restrict__ bp,
                        float* __restrict__ pattT){
  __shared__ float xs[160 * 68];              // 43.5 KB
  __shared__ float wl[16 * 164];              // 10.5 KB
  int blk = blockIdx.x;
  int jt = blk & 15; int t = blk >> 4;
  int cog = t % 10; int b = t / 10;
  int co0 = cog * 16, j0t = jt * 64;
  int tid = threadIdx.x;
  const float* xb = pconv + (size_t)(b * NC3) * L3P + j0t;
  for (int i = tid; i < 2720; i += 128){      // 160 rows x 17 f4, relu at stage
    int r = i / 17, c = i % 17;
    float4 v = *(const float4*)(xb + (size_t)r * L3P + c * 4);
    *(float4*)(&xs[r * 68 + c * 4]) = relu4_(v);
  }
  for (int i = tid; i < 640; i += 128){       // 16 co x 40 f4
    int cc = i / 40, c = i % 40;
    *(float4*)(&wl[cc * 164 + c * 4]) =
        *(const float4*)(Wp + (size_t)(co0 + cc) * NC3 + c * 4);
  }
  __syncthreads();
  int cp = tid >> 4, jg = tid & 15;
  int j0 = jg * 4;
  float acc0[4] = {0,0,0,0}, acc1[4] = {0,0,0,0};
  const float* xcol = xs + j0;
  const float* w0r = wl + (cp * 2) * 164;
  const float* w1r = wl + (cp * 2 + 1) * 164;
  #pragma unroll 2
  for (int k4 = 0; k4 < 40; k4++){
    float4 wa = *(const float4*)(w0r + k4 * 4);
    float4 wb = *(const float4*)(w1r + k4 * 4);
    float4 x0 = *(const float4*)(xcol + (k4 * 4 + 0) * 68);
    float4 x1 = *(const float4*)(xcol + (k4 * 4 + 1) * 68);
    float4 x2 = *(const float4*)(xcol + (k4 * 4 + 2) * 68);
    float4 x3 = *(const float4*)(xcol + (k4 * 4 + 3) * 68);
    acc0[0] = fmaf(x0.x, wa.x, fmaf(x1.x, wa.y, fmaf(x2.x, wa.z, fmaf(x3.x, wa.w, acc0[0]))));
    acc0[1] = fmaf(x0.y, wa.x, fmaf(x1.y, wa.y, fmaf(x2.y, wa.z, fmaf(x3.y, wa.w, acc0[1]))));
    acc0[2] = fmaf(x0.z, wa.x, fmaf(x1.z, wa.y, fmaf(x2.z, wa.z, fmaf(x3.z, wa.w, acc0[2]))));
    acc0[3] = fmaf(x0.w, wa.x, fmaf(x1.w, wa.y, fmaf(x2.w, wa.z, fmaf(x3.w, wa.w, acc0[3]))));
    acc1[0] = fmaf(x0.x, wb.x, fmaf(x1.x, wb.y, fmaf(x2.x, wb.z, fmaf(x3.x, wb.w, acc1[0]))));
    acc1[1] = fmaf(x0.y, wb.x, fmaf(x1.y, wb.y, fmaf(x2.y, wb.z, fmaf(x3.y, wb.w, acc1[1]))));
    acc1[2] = fmaf(x0.z, wb.x, fmaf(x1.z, wb.y, fmaf(x2.z, wb.z, fmaf(x3.z, wb.w, acc1[2]))));
    acc1[3] = fmaf(x0.w, wb.x, fmaf(x1.w, wb.y, fmaf(x2.w, wb.z, fmaf(x3.w, wb.w, acc1[3]))));
  }
  int coA = co0 + cp * 2, coB = coA + 1;
  float bA = bp[coA], bB = bp[coB];
  int jb = j0t + j0;
  const int* pr = prot + b * PL;
  #pragma unroll
  for (int q = 0; q < 4; q++){
    int j = jb + q;
    if (j < L3O){
      bool act = pr[j] > 0;
      pattT[(size_t)(b * NC3 + coA) * PLP + j] = act ? (acc0[q] + bA) : 0.f;
      pattT[(size_t)(b * NC3 + coB) * PLP + j] = act ? (acc1[q] + bB) : 0.f;
    }
  }
}

// ---- means of relu(da_i + pa_j): block=(b,c) ----
__global__ __launch_bounds__(256) void k_means(const float* __restrict__ dattT,
                        const float* __restrict__ pattT,
                        float* __restrict__ cmeanT, float* __restrict__ pmeanT){
  __shared__ float4 sda4[DLP / 4];
  __shared__ float4 spa4[PLP / 4];
  float* sda = (float*)sda4;
  float* spa = (float*)spa4;
  int b = blockIdx.x / NC3, c = blockIdx.x % NC3;
  int tid = threadIdx.x;
  const float4* dr = (const float4*)(dattT + (size_t)(b * NC3 + c) * DLP);
  const float4* pr = (const float4*)(pattT + (size_t)(b * NC3 + c) * PLP);
  if (tid < DLP / 4) sda4[tid] = dr[tid];
  if (tid < PLP / 4) spa4[tid] = pr[tid];
  __syncthreads();
  if (tid < DL){
    float v = sda[tid];
    float s0 = 0.f, s1 = 0.f, s2 = 0.f, s3 = 0.f;
    for (int j4 = 0; j4 < 244; j4++){
      float4 p = spa4[j4];
      s0 += relu_(v + p.x); s1 += relu_(v + p.y);
      s2 += relu_(v + p.z); s3 += relu_(v + p.w);
    }
    s0 += relu_(v + spa[976]) + relu_(v + spa[977]) + relu_(v + spa[978]);
    cmeanT[(size_t)(b * NC3 + c) * DLP + tid] = (s0 + s1 + s2 + s3) * (1.f / L3O);
  }
  for (int j = tid; j < L3O; j += 256){
    float v = spa[j];
    float s0 = 0.f, s1 = 0.f, s2 = 0.f, s3 = 0.f;
    for (int i4 = 0; i4 < 37; i4++){
      float4 d = sda4[i4];
      s0 += relu_(v + d.x); s1 += relu_(v + d.y);
      s2 += relu_(v + d.z); s3 += relu_(v + d.w);
    }
    s0 += relu_(v + sda[148]) + relu_(v + sda[149]);
    pmeanT[(size_t)(b * NC3 + c) * PLP + j] = (s0 + s1 + s2 + s3) * (1.f / DL);
  }
}

// ---- compound gate + max-pool (80 blocks x 256) ----
__global__ __launch_bounds__(256) void k_atteC(const float* __restrict__ cmeanT,
                        const float* __restrict__ Watt, const float* __restrict__ batt,
                        const float* __restrict__ drug, unsigned* __restrict__ enc){
  __shared__ float sred[4][8];
  int blk = blockIdx.x;
  int b = blk / 20, c0 = (blk % 20) * 8;
  float m[8];
  #pragma unroll
  for (int cc = 0; cc < 8; cc++) m[cc] = NINF;
  int i = threadIdx.x;
  if (i < DL){
    float acc[8];
    #pragma unroll
    for (int cc = 0; cc < 8; cc++) acc[cc] = batt[c0 + cc];
    const float* xc = cmeanT + (size_t)b * NC3 * DLP + i;
    const float* wr = Watt + (size_t)c0 * NC3;
    for (int cb = 0; cb < NC3; cb += 32){
      float xv[32];
      #pragma unroll
      for (int u = 0; u < 32; u++) xv[u] = xc[(size_t)(cb + u) * DLP];
      #pragma unroll
      for (int u = 0; u < 32; u++){
        #pragma unroll
        for (int cc = 0; cc < 8; cc++)
          acc[cc] = fmaf(xv[u], wr[(size_t)cc * NC3 + cb + u], acc[cc]);
      }
    }
    const float* gr = drug + ((size_t)b * DL + i) * NC3 + c0;
    #pragma unroll
    for (int cc = 0; cc < 8; cc++){
      float atte = 1.f / (1.f + expf(-acc[cc]));
      m[cc] = gr[cc] * (0.5f + atte);
    }
  }
  int wave = threadIdx.x >> 6, lane = threadIdx.x & 63;
  #pragma unroll
  for (int cc = 0; cc < 8; cc++){
    float v = m[cc];
    for (int off = 1; off < 64; off <<= 1) v = fmaxf(v, __shfl_xor(v, off, 64));
    if (lane == 0) sred[wave][cc] = v;
  }
  __syncthreads();
  if (threadIdx.x < 8){
    float v = fmaxf(fmaxf(sred[0][threadIdx.x], sred[1][threadIdx.x]),
                    fmaxf(sred[2][threadIdx.x], sred[3][threadIdx.x]));
    atomicMax(&enc[b * NC3 + c0 + threadIdx.x], fenc(v));
  }
}

// ---- protein gate + max-pool, tiled: grid 640 = b x cog(16co) x jt(64j) ----
__global__ __launch_bounds__(128) void k_atteP(const float* __restrict__ pmeanT,
                        const float* __restrict__ Watt, const float* __restrict__ batt,
                        const float* __restrict__ pconv, unsigned* __restrict__ enc){
  __shared__ float xs[160 * 68];              // 43.5 KB
  __shared__ float wl[16 * 164];              // 10.5 KB
  int blk = blockIdx.x;
  int jt = blk & 15; int t = blk >> 4;
  int cog = t % 10; int b = t / 10;
  int co0 = cog * 16, j0t = jt * 64;
  int tid = threadIdx.x;
  const float* xb = pmeanT + (size_t)(b * NC3) * PLP + j0t;
  for (int i = tid; i < 2720; i += 128){      // 160 rows x 17 f4
    int r = i / 17, c = i % 17;
    *(float4*)(&xs[r * 68 + c * 4]) = *(const float4*)(xb + (size_t)r * PLP + c * 4);
  }
  for (int i = tid; i < 640; i += 128){
    int cc = i / 40, c = i % 40;
    *(float4*)(&wl[cc * 164 + c * 4]) =
        *(const float4*)(Watt + (size_t)(co0 + cc) * NC3 + c * 4);
  }
  __syncthreads();
  int cp = tid >> 4, jg = tid & 15;
  int j0 = jg * 4;
  float acc0[4] = {0,0,0,0}, acc1[4] = {0,0,0,0};
  const float* xcol = xs + j0;
  const float* w0r = wl + (cp * 2) * 164;
  const float* w1r = wl + (cp * 2 + 1) * 164;
  #pragma unroll 2
  for (int k4 = 0; k4 < 40; k4++){
    float4 wa = *(const float4*)(w0r + k4 * 4);
    float4 wb = *(const float4*)(w1r + k4 * 4);
    float4 x0 = *(const float4*)(xcol + (k4 * 4 + 0) * 68);
    float4 x1 = *(const float4*)(xcol + (k4 * 4 + 1) * 68);
    float4 x2 = *(const float4*)(xcol + (k4 * 4 + 2) * 68);
    float4 x3 = *(const float4*)(xcol + (k4 * 4 + 3) * 68);
    acc0[0] = fmaf(x0.x, wa.x, fmaf(x1.x, wa.y, fmaf(x2.x, wa.z, fmaf(x3.x, wa.w, acc0[0]))));
    acc0[1] = fmaf(x0.y, wa.x, fmaf(x1.y, wa.y, fmaf(x2.y, wa.z, fmaf(x3.y, wa.w, acc0[1]))));
    acc0[2] = fmaf(x0.z, wa.x, fmaf(x1.z, wa.y, fmaf(x2.z, wa.z, fmaf(x3.z, wa.w, acc0[2]))));
    acc0[3] = fmaf(x0.w, wa.x, fmaf(x1.w, wa.y, fmaf(x2.w, wa.z, fmaf(x3.w, wa.w, acc0[3]))));
    acc1[0] = fmaf(x0.x, wb.x, fmaf(x1.x, wb.y, fmaf(x2.x, wb.z, fmaf(x3.x, wb.w, acc1[0]))));
    acc1[1] = fmaf(x0.y, wb.x, fmaf(x1.y, wb.y, fmaf(x2.y, wb.z, fmaf(x3.y, wb.w, acc1[1]))));
    acc1[2] = fmaf(x0.z, wb.x, fmaf(x1.z, wb.y, fmaf(x2.z, wb.z, fmaf(x3.z, wb.w, acc1[2]))));
    acc1[3] = fmaf(x0.w, wb.x, fmaf(x1.w, wb.y, fmaf(x2.w, wb.z, fmaf(x3.w, wb.w, acc1[3]))));
  }
  int coA = co0 + cp * 2, coB = coA + 1;
  float bA = batt[coA], bB = batt[coB];
  int jb = j0t + j0;
  float mA = NINF, mB = NINF;
  if (jb < L3P){
    float4 pA = *(const float4*)(pconv + (size_t)(b * NC3 + coA) * L3P + jb);
    float4 pB = *(const float4*)(pconv + (size_t)(b * NC3 + coB) * L3P + jb);
    float pAr[4] = {pA.x, pA.y, pA.z, pA.w};
    float pBr[4] = {pB.x, pB.y, pB.z, pB.w};
    #pragma unroll
    for (int q = 0; q < 4; q++){
      int j = jb + q;
      if (j < L3O){
        float gA = 1.f / (1.f + expf(-(acc0[q] + bA)));
        float gB = 1.f / (1.f + expf(-(acc1[q] + bB)));
        mA = fmaxf(mA, relu_(pAr[q]) * (0.5f + gA));
        mB = fmaxf(mB, relu_(pBr[q]) * (0.5f + gB));
      }
    }
  }
  #pragma unroll
  for (int off = 1; off < 16; off <<= 1){
    mA = fmaxf(mA, __shfl_xor(mA, off, 64));
    mB = fmaxf(mB, __shfl_xor(mB, off, 64));
  }
  if (jg == 0){
    atomicMax(&enc[BB * NC3 + b * NC3 + coA], fenc(mA));
    atomicMax(&enc[BB * NC3 + b * NC3 + coB], fenc(mB));
  }
}

// ---- MLP 1: 320 -> 1024 ----
__global__ __launch_bounds__(256) void k_mlp1(const unsigned* __restrict__ enc,
                        const float* __restrict__ W1, const float* __restrict__ bf1,
                        float* __restrict__ f1){
  int b = blockIdx.x >> 4;
  int o = (blockIdx.x & 15) * 64 + (threadIdx.x >> 2);
  int q = threadIdx.x & 3;
  int k0 = q * 80;
  const float4* wr = (const float4*)(W1 + (size_t)o * 320 + k0);
  float4 a = make_float4(0.f, 0.f, 0.f, 0.f);
  for (int mI = 0; mI < 20; mI++){
    float4 wv = wr[mI];
    int k = k0 + mI * 4;
    const unsigned* e = (k < 160) ? (enc + b * NC3 + k) : (enc + BB * NC3 + b * NC3 + (k - 160));
    a.x = fmaf(fdec(e[0]), wv.x, a.x);
    a.y = fmaf(fdec(e[1]), wv.y, a.y);
    a.z = fmaf(fdec(e[2]), wv.z, a.z);
    a.w = fmaf(fdec(e[3]), wv.w, a.w);
  }
  float r = a.x + a.y + a.z + a.w;
  r += __shfl_xor(r, 1, 64);
  r += __shfl_xor(r, 2, 64);
  if (q == 0) f1[b * 1024 + o] = lrelu_(r + bf1[o]);
}

// ---- MLP 2: 1024 -> 1024 ----
__global__ __launch_bounds__(256) void k_mlp2(const float* __restrict__ x,
                        const float* __restrict__ W, const float* __restrict__ bias,
                        float* __restrict__ y){
  int b = blockIdx.x >> 4;
  int o = (blockIdx.x & 15) * 64 + (threadIdx.x >> 2);
  int q = threadIdx.x & 3;
  int k0 = q * 256;
  const float4* wr = (const float4*)(W + (size_t)o * 1024 + k0);
  const float4* xr = (const float4*)(x + b * 1024 + k0);
  float4 a = make_float4(0.f, 0.f, 0.f, 0.f);
  #pragma unroll 4
  for (int mI = 0; mI < 64; mI++){
    float4 wv = wr[mI], xv = xr[mI];
    a.x = fmaf(xv.x, wv.x, a.x);
    a.y = fmaf(xv.y, wv.y, a.y);
    a.z = fmaf(xv.z, wv.z, a.z);
    a.w = fmaf(xv.w, wv.w, a.w);
  }
  float r = a.x + a.y + a.z + a.w;
  r += __shfl_xor(r, 1, 64);
  r += __shfl_xor(r, 2, 64);
  if (q == 0) y[b * 1024 + o] = lrelu_(r + bias[o]);
}

// ---- MLP 3: 1024 -> 512 ----
__global__ __launch_bounds__(256) void k_mlp3(const float* __restrict__ x,
                        const float* __restrict__ W, const float* __restrict__ bias,
                        float* __restrict__ y){
  int b = blockIdx.x >> 3;
  int o = (blockIdx.x & 7) * 64 + (threadIdx.x >> 2);
  int q = threadIdx.x & 3;
  int k0 = q * 256;
  const float4* wr = (const float4*)(W + (size_t)o * 1024 + k0);
  const float4* xr = (const float4*)(x + b * 1024 + k0);
  float4 a = make_float4(0.f, 0.f, 0.f, 0.f);
  #pragma unroll 4
  for (int mI = 0; mI < 64; mI++){
    float4 wv = wr[mI], xv = xr[mI];
    a.x = fmaf(xv.x, wv.x, a.x);
    a.y = fmaf(xv.y, wv.y, a.y);
    a.z = fmaf(xv.z, wv.z, a.z);
    a.w = fmaf(xv.w, wv.w, a.w);
  }
  float r = a.x + a.y + a.z + a.w;
  r += __shfl_xor(r, 1, 64);
  r += __shfl_xor(r, 2, 64);
  if (q == 0) y[b * 512 + o] = lrelu_(r + bias[o]);
}

// ---- MLP out: 512 -> 2 ----
__global__ void k_mlp4(const float* __restrict__ f3, const float* __restrict__ Wo,
                       const float* __restrict__ bo, float* __restrict__ out){
  int tid = threadIdx.x;
  int g = tid >> 5, lane = tid & 31;
  int b = g >> 1, o = g & 1;
  const float4* xr = (const float4*)(f3 + b * 512);
  const float4* wr = (const float4*)(Wo + o * 512);
  float4 a = make_float4(0.f, 0.f, 0.f, 0.f);
  #pragma unroll
  for (int mI = 0; mI < 4; mI++){
    int k4 = lane + mI * 32;
    float4 xv = xr[k4], wv = wr[k4];
    a.x = fmaf(xv.x, wv.x, a.x);
    a.y = fmaf(xv.y, wv.y, a.y);
    a.z = fmaf(xv.z, wv.z, a.z);
    a.w = fmaf(xv.w, wv.w, a.w);
  }
  float r = a.x + a.y + a.z + a.w;
  for (int off = 16; off; off >>= 1) r += __shfl_xor(r, off, 64);
  if (lane == 0) out[b * 2 + o] = r + bo[o];
}

extern "C" void kernel_launch(void* const* d_in, const int* in_sizes, int n_in,
                              void* d_out, int out_size, void* d_ws, size_t ws_size,
                              hipStream_t stream) {
  const float* drug  = (const float*)d_in[0];
  const int*   natoms= (const int*)d_in[1];
  const int*   prot  = (const int*)d_in[2];
  const float* emb   = (const float*)d_in[3];
  const float* w1    = (const float*)d_in[4];
  const float* b1    = (const float*)d_in[5];
  const float* w2    = (const float*)d_in[6];
  const float* b2    = (const float*)d_in[7];
  const float* w3    = (const float*)d_in[8];
  const float* b3    = (const float*)d_in[9];
  const float* Wd    = (const float*)d_in[10];
  const float* bd    = (const float*)d_in[11];
  const float* Wp    = (const float*)d_in[12];
  const float* bp    = (const float*)d_in[13];
  const float* Watt  = (const float*)d_in[14];
  const float* batt  = (const float*)d_in[15];
  const float* W1    = (const float*)d_in[16];
  const float* bf1   = (const float*)d_in[17];
  const float* W2    = (const float*)d_in[18];
  const float* bf2   = (const float*)d_in[19];
  const float* W3    = (const float*)d_in[20];
  const float* bf3   = (const float*)d_in[21];
  const float* Wo    = (const float*)d_in[22];
  const float* bo    = (const float*)d_in[23];
  float* out = (float*)d_out;

  float* ws = (float*)d_ws;
  float* h1     = ws;                       // 160000 (dead after conv2s)
  float* cmeanT = ws;                       // 97280 (reuse of h1 region)
  float* f1     = ws + 97280;               // 4096
  float* f2     = ws + 101376;              // 4096
  float* f3     = ws + 105472;              // 2048
  float* h2     = ws + 160000;              // 317440 (pre-relu, atomic accum)
  float* pconv  = ws + 477440;              // 627200 (pre-relu, atomic accum)
  float* dattT  = ws + 1104640;             // 97280
  float* pattT  = ws + 1201920;             // 629760
  float* pmeanT = ws + 1831680;             // 629760
  unsigned* enc = (unsigned*)(ws + 2461440);// 1280 u32
  float* projG  = ws + 2461760;             // 4186

  // zero the split-K accumulation buffers (h2 + pconv are adjacent)
  hipMemsetAsync(h2, 0, (size_t)(317440 + 627200) * sizeof(float), stream);

  k_proj  <<<17, 256, 0, stream>>>(emb, w1, projG);
  k_conv1 <<<BB * 80, 256, 0, stream>>>(prot, projG, b1, h1);
  k_conv2s<<<640, 128, 0, stream>>>(h1, w2, b2, h2);
  k_conv3s<<<1280, 128, 0, stream>>>(h2, w3, b3, pconv);
  k_datt  <<<80, 256, 0, stream>>>(drug, natoms, Wd, bd, dattT, enc);
  k_patt  <<<640, 128, 0, stream>>>(pconv, prot, Wp, bp, pattT);
  k_means <<<BB * NC3, 256, 0, stream>>>(dattT, pattT, cmeanT, pmeanT);
  k_atteC <<<80, 256, 0, stream>>>(cmeanT, Watt, batt, drug, enc);
  k_atteP <<<640, 128, 0, stream>>>(pmeanT, Watt, batt, pconv, enc);
  k_mlp1  <<<64, 256, 0, stream>>>(enc, W1, bf1, f1);
  k_mlp2  <<<64, 256, 0, stream>>>(f1, W2, bf2, f2);
  k_mlp3  <<<32, 256, 0, stream>>>(f2, W3, bf3, f3);
  k_mlp4  <<<1, 256, 0, stream>>>(f3, Wo, bo, out);
}

// Round 6
// 191.746 us; speedup vs baseline: 1.2780x; 1.2780x over previous
//
#include <hip/hip_runtime.h>
#include <math.h>

#define BB 4
#define DL 150
#define PL 1000
#define CD 64
#define NC1 40
#define NC2 80
#define NC3 160
#define L1O 997
#define L2O 990
#define L3O 979
#define L1P 1000
#define L2P 992
#define L3P 980
#define DLP 152
#define PLP 984
#define NINF (-1e30f)

__device__ __forceinline__ float relu_(float x){ return fmaxf(x, 0.f); }
__device__ __forceinline__ float lrelu_(float x){ return x > 0.f ? x : 0.01f * x; }

__device__ __forceinline__ unsigned fenc(float x){
  unsigned u = __float_as_uint(x);
  return (u & 0x80000000u) ? ~u : (u | 0x80000000u);
}
__device__ __forceinline__ float fdec(unsigned u){
  return __uint_as_float((u & 0x80000000u) ? (u & 0x7fffffffu) : ~u);
}
__device__ __forceinline__ float4 relu4_(float4 v){
  v.x = fmaxf(v.x, 0.f); v.y = fmaxf(v.y, 0.f);
  v.z = fmaxf(v.z, 0.f); v.w = fmaxf(v.w, 0.f);
  return v;
}

// ---- proj table ----
__global__ void k_proj(const float* __restrict__ emb, const float* __restrict__ w1,
                       float* __restrict__ projG){
  int e = blockIdx.x * 256 + threadIdx.x;
  if (e >= 26 * 160) return;
  int tok = e / 160, rem = e % 160, k = rem / 40, co = rem % 40;
  float a = 0.f;
  const float* er = emb + tok * CD;
  const float* wr = w1 + co * (CD * 4) + k;
  #pragma unroll 8
  for (int ci = 0; ci < CD; ci++) a = fmaf(er[ci], wr[ci * 4], a);
  projG[tok * 161 + k * 40 + co] = a;
}

// ---- conv1 apply (writes relu'd h1) ----
__global__ __launch_bounds__(256) void k_conv1(const int* __restrict__ prot,
                        const float* __restrict__ projG, const float* __restrict__ b1,
                        float* __restrict__ h1){
  __shared__ float sp[26 * 161];
  int b = blockIdx.x / 80;
  int t = (blockIdx.x % 80) * 256 + threadIdx.x;
  for (int k = threadIdx.x; k < 26 * 161; k += 256) sp[k] = projG[k];
  __syncthreads();
  int p = t & 1023, co2 = t >> 10;
  if (p >= L1O) return;
  const int* pr = prot + b * PL + p;
  int t0 = pr[0], t1 = pr[1], t2 = pr[2], t3 = pr[3];
  #pragma unroll
  for (int c = 0; c < 2; c++){
    int co = co2 * 2 + c;
    float a = b1[co] + sp[t0 * 161 + co] + sp[t1 * 161 + 40 + co]
            + sp[t2 * 161 + 80 + co] + sp[t3 * 161 + 120 + co];
    h1[(size_t)(b * NC1 + co) * L1P + p] = relu_(a);
  }
}

// ---- conv2 direct-global: grid 640 = b(4) x co(80) x pt(2), 128 thr, 4p/thread ----
// W row is block-uniform -> scalar loads; X via coalesced float4 sliding window.
__global__ __launch_bounds__(128) void k_conv2g(const float* __restrict__ h1,
                        const float* __restrict__ w, const float* __restrict__ bias,
                        float* __restrict__ h2){
  int blk = blockIdx.x;
  int pt = blk & 1; int t = blk >> 1;
  int co = t % NC2; int b = t / NC2;
  int p0 = pt * 512 + threadIdx.x * 4;
  if (p0 >= L2O) return;
  const float* xb = h1 + (size_t)(b * NC1) * L1P + p0;
  const float4* wr4 = (const float4*)(w + (size_t)co * 320);
  float a0 = 0.f, a1 = 0.f, a2 = 0.f, a3 = 0.f;
  #pragma unroll 4
  for (int ci = 0; ci < NC1; ci++){
    const float4* xr = (const float4*)(xb + (size_t)ci * L1P);
    float4 v0 = xr[0], v1 = xr[1], v2 = xr[2];
    float xv[12];
    *(float4*)(&xv[0]) = v0; *(float4*)(&xv[4]) = v1; *(float4*)(&xv[8]) = v2;
    float4 w0 = wr4[ci * 2], w1v = wr4[ci * 2 + 1];
    float wk[8];
    *(float4*)(&wk[0]) = w0; *(float4*)(&wk[4]) = w1v;
    #pragma unroll
    for (int k = 0; k < 8; k++){
      a0 = fmaf(xv[k],     wk[k], a0);
      a1 = fmaf(xv[k + 1], wk[k], a1);
      a2 = fmaf(xv[k + 2], wk[k], a2);
      a3 = fmaf(xv[k + 3], wk[k], a3);
    }
  }
  float bv = bias[co];
  float* yr = h2 + (size_t)(b * NC2 + co) * L2P + p0;
  if (p0 + 3 < L2O){
    float4 o; o.x = relu_(a0 + bv); o.y = relu_(a1 + bv);
    o.z = relu_(a2 + bv); o.w = relu_(a3 + bv);
    *(float4*)yr = o;
  } else {
    float aa[4] = {a0, a1, a2, a3};
    #pragma unroll
    for (int j = 0; j < 4; j++) if (p0 + j < L2O) yr[j] = relu_(aa[j] + bv);
  }
}

// ---- conv3 direct-global: grid 1280 = b(4) x co(160) x pt(2), 128 thr, 4p/thread ----
__global__ __launch_bounds__(128) void k_conv3g(const float* __restrict__ h2,
                        const float* __restrict__ w, const float* __restrict__ bias,
                        float* __restrict__ pconv){
  int blk = blockIdx.x;
  int pt = blk & 1; int t = blk >> 1;
  int co = t % NC3; int b = t / NC3;
  int p0 = pt * 512 + threadIdx.x * 4;
  if (p0 >= L3O) return;
  const float* xb = h2 + (size_t)(b * NC2) * L2P + p0;
  const float4* wr4 = (const float4*)(w + (size_t)co * 960);
  float a0 = 0.f, a1 = 0.f, a2 = 0.f, a3 = 0.f;
  #pragma unroll 2
  for (int ci = 0; ci < NC2; ci++){
    const float4* xr = (const float4*)(xb + (size_t)ci * L2P);
    float4 v0 = xr[0], v1 = xr[1], v2 = xr[2], v3 = xr[3];
    float xv[16];
    *(float4*)(&xv[0])  = v0; *(float4*)(&xv[4])  = v1;
    *(float4*)(&xv[8])  = v2; *(float4*)(&xv[12]) = v3;
    float4 w0 = wr4[ci * 3], w1v = wr4[ci * 3 + 1], w2v = wr4[ci * 3 + 2];
    float wk[12];
    *(float4*)(&wk[0]) = w0; *(float4*)(&wk[4]) = w1v; *(float4*)(&wk[8]) = w2v;
    #pragma unroll
    for (int k = 0; k < 12; k++){
      a0 = fmaf(xv[k],     wk[k], a0);
      a1 = fmaf(xv[k + 1], wk[k], a1);
      a2 = fmaf(xv[k + 2], wk[k], a2);
      a3 = fmaf(xv[k + 3], wk[k], a3);
    }
  }
  float bv = bias[co];
  float* yr = pconv + (size_t)(b * NC3 + co) * L3P + p0;
  if (p0 + 3 < L3O){
    float4 o; o.x = relu_(a0 + bv); o.y = relu_(a1 + bv);
    o.z = relu_(a2 + bv); o.w = relu_(a3 + bv);
    *(float4*)yr = o;
  } else {
    float aa[4] = {a0, a1, a2, a3};
    #pragma unroll
    for (int j = 0; j < 4; j++) if (p0 + j < L3O) yr[j] = relu_(aa[j] + bv);
  }
}

// ---- drug attention (80 blocks x 256) + enc init ----
__global__ __launch_bounds__(256) void k_datt(const float* __restrict__ drug,
                        const int* __restrict__ natoms,
                        const float* __restrict__ Wd, const float* __restrict__ bd,
                        float* __restrict__ dattT, unsigned* __restrict__ enc){
  int blk = blockIdx.x;
  if (blk == 0){
    for (int k = threadIdx.x; k < 2 * BB * NC3; k += 256) enc[k] = 0u;
  }
  int b = blk / 20, c0 = (blk % 20) * 8;
  int i = threadIdx.x;
  if (i >= DL) return;
  const float4* xr = (const float4*)(drug + ((size_t)b * DL + i) * NC3);
  float4 a[8];
  #pragma unroll
  for (int cc = 0; cc < 8; cc++) a[cc] = make_float4(0.f, 0.f, 0.f, 0.f);
  for (int k4 = 0; k4 < 40; k4++){
    float4 xv = xr[k4];
    #pragma unroll
    for (int cc = 0; cc < 8; cc++){
      float4 wv = ((const float4*)(Wd + (size_t)(c0 + cc) * NC3))[k4];
      a[cc].x = fmaf(xv.x, wv.x, a[cc].x);
      a[cc].y = fmaf(xv.y, wv.y, a[cc].y);
      a[cc].z = fmaf(xv.z, wv.z, a[cc].z);
      a[cc].w = fmaf(xv.w, wv.w, a[cc].w);
    }
  }
  bool act = i < natoms[b];
  #pragma unroll
  for (int cc = 0; cc < 8; cc++){
    float r = act ? (a[cc].x + a[cc].y + a[cc].z + a[cc].w + bd[c0 + cc]) : 0.f;
    dattT[(size_t)(b * NC3 + c0 + cc) * DLP + i] = r;
  }
}

// ---- protein attention, tiled GEMM ----
__global__ __launch_bounds__(128) void k_patt(const float* __restrict__ pconv,
                        const int* __restrict__ prot,
                        const float* __restrict__ Wp, const float* __restrict__ bp,
                        float* __restrict__ pattT){
  __shared__ float xs[160 * 68];
  __shared__ float wl[16 * 164];
  int blk = blockIdx.x;
  int jt = blk & 15; int t = blk >> 4;
  int cog = t % 10; int b = t / 10;
  int co0 = cog * 16, j0t = jt * 64;
  int tid = threadIdx.x;
  const float* xb = pconv + (size_t)(b * NC3) * L3P + j0t;
  for (int i = tid; i < 2720; i += 128){
    int r = i / 17, c = i % 17;
    float4 v = *(const float4*)(xb + (size_t)r * L3P + c * 4);
    *(float4*)(&xs[r * 68 + c * 4]) = relu4_(v);
  }
  for (int i = tid; i < 640; i += 128){
    int cc = i / 40, c = i % 40;
    *(float4*)(&wl[cc * 164 + c * 4]) =
        *(const float4*)(Wp + (size_t)(co0 + cc) * NC3 + c * 4);
  }
  __syncthreads();
  int cp = tid >> 4, jg = tid & 15;
  int j0 = jg * 4;
  float acc0[4] = {0,0,0,0}, acc1[4] = {0,0,0,0};
  const float* xcol = xs + j0;
  const float* w0r = wl + (cp * 2) * 164;
  const float* w1r = wl + (cp * 2 + 1) * 164;
  #pragma unroll 2
  for (int k4 = 0; k4 < 40; k4++){
    float4 wa = *(const float4*)(w0r + k4 * 4);
    float4 wb = *(const float4*)(w1r + k4 * 4);
    float4 x0 = *(const float4*)(xcol + (k4 * 4 + 0) * 68);
    float4 x1 = *(const float4*)(xcol + (k4 * 4 + 1) * 68);
    float4 x2 = *(const float4*)(xcol + (k4 * 4 + 2) * 68);
    float4 x3 = *(const float4*)(xcol + (k4 * 4 + 3) * 68);
    acc0[0] = fmaf(x0.x, wa.x, fmaf(x1.x, wa.y, fmaf(x2.x, wa.z, fmaf(x3.x, wa.w, acc0[0]))));
    acc0[1] = fmaf(x0.y, wa.x, fmaf(x1.y, wa.y, fmaf(x2.y, wa.z, fmaf(x3.y, wa.w, acc0[1]))));
    acc0[2] = fmaf(x0.z, wa.x, fmaf(x1.z, wa.y, fmaf(x2.z, wa.z, fmaf(x3.z, wa.w, acc0[2]))));
    acc0[3] = fmaf(x0.w, wa.x, fmaf(x1.w, wa.y, fmaf(x2.w, wa.z, fmaf(x3.w, wa.w, acc0[3]))));
    acc1[0] = fmaf(x0.x, wb.x, fmaf(x1.x, wb.y, fmaf(x2.x, wb.z, fmaf(x3.x, wb.w, acc1[0]))));
    acc1[1] = fmaf(x0.y, wb.x, fmaf(x1.y, wb.y, fmaf(x2.y, wb.z, fmaf(x3.y, wb.w, acc1[1]))));
    acc1[2] = fmaf(x0.z, wb.x, fmaf(x1.z, wb.y, fmaf(x2.z, wb.z, fmaf(x3.z, wb.w, acc1[2]))));
    acc1[3] = fmaf(x0.w, wb.x, fmaf(x1.w, wb.y, fmaf(x2.w, wb.z, fmaf(x3.w, wb.w, acc1[3]))));
  }
  int coA = co0 + cp * 2, coB = coA + 1;
  float bA = bp[coA], bB = bp[coB];
  int jb = j0t + j0;
  const int* pr = prot + b * PL;
  #pragma unroll
  for (int q = 0; q < 4; q++){
    int j = jb + q;
    if (j < L3O){
      bool act = pr[j] > 0;
      pattT[(size_t)(b * NC3 + coA) * PLP + j] = act ? (acc0[q] + bA) : 0.f;
      pattT[(size_t)(b * NC3 + coB) * PLP + j] = act ? (acc1[q] + bB) : 0.f;
    }
  }
}

// ---- means of relu(da_i + pa_j): block=(b,c) ----
__global__ __launch_bounds__(256) void k_means(const float* __restrict__ dattT,
                        const float* __restrict__ pattT,
                        float* __restrict__ cmeanT, float* __restrict__ pmeanT){
  __shared__ float4 sda4[DLP / 4];
  __shared__ float4 spa4[PLP / 4];
  float* sda = (float*)sda4;
  float* spa = (float*)spa4;
  int b = blockIdx.x / NC3, c = blockIdx.x % NC3;
  int tid = threadIdx.x;
  const float4* dr = (const float4*)(dattT + (size_t)(b * NC3 + c) * DLP);
  const float4* pr = (const float4*)(pattT + (size_t)(b * NC3 + c) * PLP);
  if (tid < DLP / 4) sda4[tid] = dr[tid];
  if (tid < PLP / 4) spa4[tid] = pr[tid];
  __syncthreads();
  if (tid < DL){
    float v = sda[tid];
    float s0 = 0.f, s1 = 0.f, s2 = 0.f, s3 = 0.f;
    for (int j4 = 0; j4 < 244; j4++){
      float4 p = spa4[j4];
      s0 += relu_(v + p.x); s1 += relu_(v + p.y);
      s2 += relu_(v + p.z); s3 += relu_(v + p.w);
    }
    s0 += relu_(v + spa[976]) + relu_(v + spa[977]) + relu_(v + spa[978]);
    cmeanT[(size_t)(b * NC3 + c) * DLP + tid] = (s0 + s1 + s2 + s3) * (1.f / L3O);
  }
  for (int j = tid; j < L3O; j += 256){
    float v = spa[j];
    float s0 = 0.f, s1 = 0.f, s2 = 0.f, s3 = 0.f;
    for (int i4 = 0; i4 < 37; i4++){
      float4 d = sda4[i4];
      s0 += relu_(v + d.x); s1 += relu_(v + d.y);
      s2 += relu_(v + d.z); s3 += relu_(v + d.w);
    }
    s0 += relu_(v + sda[148]) + relu_(v + sda[149]);
    pmeanT[(size_t)(b * NC3 + c) * PLP + j] = (s0 + s1 + s2 + s3) * (1.f / DL);
  }
}

// ---- compound gate + max-pool (80 blocks x 256) ----
__global__ __launch_bounds__(256) void k_atteC(const float* __restrict__ cmeanT,
                        const float* __restrict__ Watt, const float* __restrict__ batt,
                        const float* __restrict__ drug, unsigned* __restrict__ enc){
  __shared__ float sred[4][8];
  int blk = blockIdx.x;
  int b = blk / 20, c0 = (blk % 20) * 8;
  float m[8];
  #pragma unroll
  for (int cc = 0; cc < 8; cc++) m[cc] = NINF;
  int i = threadIdx.x;
  if (i < DL){
    float acc[8];
    #pragma unroll
    for (int cc = 0; cc < 8; cc++) acc[cc] = batt[c0 + cc];
    const float* xc = cmeanT + (size_t)b * NC3 * DLP + i;
    const float* wr = Watt + (size_t)c0 * NC3;
    for (int cb = 0; cb < NC3; cb += 32){
      float xv[32];
      #pragma unroll
      for (int u = 0; u < 32; u++) xv[u] = xc[(size_t)(cb + u) * DLP];
      #pragma unroll
      for (int u = 0; u < 32; u++){
        #pragma unroll
        for (int cc = 0; cc < 8; cc++)
          acc[cc] = fmaf(xv[u], wr[(size_t)cc * NC3 + cb + u], acc[cc]);
      }
    }
    const float* gr = drug + ((size_t)b * DL + i) * NC3 + c0;
    #pragma unroll
    for (int cc = 0; cc < 8; cc++){
      float atte = 1.f / (1.f + expf(-acc[cc]));
      m[cc] = gr[cc] * (0.5f + atte);
    }
  }
  int wave = threadIdx.x >> 6, lane = threadIdx.x & 63;
  #pragma unroll
  for (int cc = 0; cc < 8; cc++){
    float v = m[cc];
    for (int off = 1; off < 64; off <<= 1) v = fmaxf(v, __shfl_xor(v, off, 64));
    if (lane == 0) sred[wave][cc] = v;
  }
  __syncthreads();
  if (threadIdx.x < 8){
    float v = fmaxf(fmaxf(sred[0][threadIdx.x], sred[1][threadIdx.x]),
                    fmaxf(sred[2][threadIdx.x], sred[3][threadIdx.x]));
    atomicMax(&enc[b * NC3 + c0 + threadIdx.x], fenc(v));
  }
}

// ---- protein gate + max-pool, tiled ----
__global__ __launch_bounds__(128) void k_atteP(const float* __restrict__ pmeanT,
                        const float* __restrict__ Watt, const float* __restrict__ batt,
                        const float* __restrict__ pconv, unsigned* __restrict__ enc){
  __shared__ float xs[160 * 68];
  __shared__ float wl[16 * 164];
  int blk = blockIdx.x;
  int jt = blk & 15; int t = blk >> 4;
  int cog = t % 10; int b = t / 10;
  int co0 = cog * 16, j0t = jt * 64;
  int tid = threadIdx.x;
  const float* xb = pmeanT + (size_t)(b * NC3) * PLP + j0t;
  for (int i = tid; i < 2720; i += 128){
    int r = i / 17, c = i % 17;
    *(float4*)(&xs[r * 68 + c * 4]) = *(const float4*)(xb + (size_t)r * PLP + c * 4);
  }
  for (int i = tid; i < 640; i += 128){
    int cc = i / 40, c = i % 40;
    *(float4*)(&wl[cc * 164 + c * 4]) =
        *(const float4*)(Watt + (size_t)(co0 + cc) * NC3 + c * 4);
  }
  __syncthreads();
  int cp = tid >> 4, jg = tid & 15;
  int j0 = jg * 4;
  float acc0[4] = {0,0,0,0}, acc1[4] = {0,0,0,0};
  const float* xcol = xs + j0;
  const float* w0r = wl + (cp * 2) * 164;
  const float* w1r = wl + (cp * 2 + 1) * 164;
  #pragma unroll 2
  for (int k4 = 0; k4 < 40; k4++){
    float4 wa = *(const float4*)(w0r + k4 * 4);
    float4 wb = *(const float4*)(w1r + k4 * 4);
    float4 x0 = *(const float4*)(xcol + (k4 * 4 + 0) * 68);
    float4 x1 = *(const float4*)(xcol + (k4 * 4 + 1) * 68);
    float4 x2 = *(const float4*)(xcol + (k4 * 4 + 2) * 68);
    float4 x3 = *(const float4*)(xcol + (k4 * 4 + 3) * 68);
    acc0[0] = fmaf(x0.x, wa.x, fmaf(x1.x, wa.y, fmaf(x2.x, wa.z, fmaf(x3.x, wa.w, acc0[0]))));
    acc0[1] = fmaf(x0.y, wa.x, fmaf(x1.y, wa.y, fmaf(x2.y, wa.z, fmaf(x3.y, wa.w, acc0[1]))));
    acc0[2] = fmaf(x0.z, wa.x, fmaf(x1.z, wa.y, fmaf(x2.z, wa.z, fmaf(x3.z, wa.w, acc0[2]))));
    acc0[3] = fmaf(x0.w, wa.x, fmaf(x1.w, wa.y, fmaf(x2.w, wa.z, fmaf(x3.w, wa.w, acc0[3]))));
    acc1[0] = fmaf(x0.x, wb.x, fmaf(x1.x, wb.y, fmaf(x2.x, wb.z, fmaf(x3.x, wb.w, acc1[0]))));
    acc1[1] = fmaf(x0.y, wb.x, fmaf(x1.y, wb.y, fmaf(x2.y, wb.z, fmaf(x3.y, wb.w, acc1[1]))));
    acc1[2] = fmaf(x0.z, wb.x, fmaf(x1.z, wb.y, fmaf(x2.z, wb.z, fmaf(x3.z, wb.w, acc1[2]))));
    acc1[3] = fmaf(x0.w, wb.x, fmaf(x1.w, wb.y, fmaf(x2.w, wb.z, fmaf(x3.w, wb.w, acc1[3]))));
  }
  int coA = co0 + cp * 2, coB = coA + 1;
  float bA = batt[coA], bB = batt[coB];
  int jb = j0t + j0;
  float mA = NINF, mB = NINF;
  if (jb < L3P){
    float4 pA = *(const float4*)(pconv + (size_t)(b * NC3 + coA) * L3P + jb);
    float4 pB = *(const float4*)(pconv + (size_t)(b * NC3 + coB) * L3P + jb);
    float pAr[4] = {pA.x, pA.y, pA.z, pA.w};
    float pBr[4] = {pB.x, pB.y, pB.z, pB.w};
    #pragma unroll
    for (int q = 0; q < 4; q++){
      int j = jb + q;
      if (j < L3O){
        float gA = 1.f / (1.f + expf(-(acc0[q] + bA)));
        float gB = 1.f / (1.f + expf(-(acc1[q] + bB)));
        mA = fmaxf(mA, relu_(pAr[q]) * (0.5f + gA));
        mB = fmaxf(mB, relu_(pBr[q]) * (0.5f + gB));
      }
    }
  }
  #pragma unroll
  for (int off = 1; off < 16; off <<= 1){
    mA = fmaxf(mA, __shfl_xor(mA, off, 64));
    mB = fmaxf(mB, __shfl_xor(mB, off, 64));
  }
  if (jg == 0){
    atomicMax(&enc[BB * NC3 + b * NC3 + coA], fenc(mA));
    atomicMax(&enc[BB * NC3 + b * NC3 + coB], fenc(mB));
  }
}

// ---- MLP 1: 320 -> 1024 ----
__global__ __launch_bounds__(256) void k_mlp1(const unsigned* __restrict__ enc,
                        const float* __restrict__ W1, const float* __restrict__ bf1,
                        float* __restrict__ f1){
  int b = blockIdx.x >> 4;
  int o = (blockIdx.x & 15) * 64 + (threadIdx.x >> 2);
  int q = threadIdx.x & 3;
  int k0 = q * 80;
  const float4* wr = (const float4*)(W1 + (size_t)o * 320 + k0);
  float4 a = make_float4(0.f, 0.f, 0.f, 0.f);
  for (int mI = 0; mI < 20; mI++){
    float4 wv = wr[mI];
    int k = k0 + mI * 4;
    const unsigned* e = (k < 160) ? (enc + b * NC3 + k) : (enc + BB * NC3 + b * NC3 + (k - 160));
    a.x = fmaf(fdec(e[0]), wv.x, a.x);
    a.y = fmaf(fdec(e[1]), wv.y, a.y);
    a.z = fmaf(fdec(e[2]), wv.z, a.z);
    a.w = fmaf(fdec(e[3]), wv.w, a.w);
  }
  float r = a.x + a.y + a.z + a.w;
  r += __shfl_xor(r, 1, 64);
  r += __shfl_xor(r, 2, 64);
  if (q == 0) f1[b * 1024 + o] = lrelu_(r + bf1[o]);
}

// ---- MLP 2: 1024 -> 1024 ----
__global__ __launch_bounds__(256) void k_mlp2(const float* __restrict__ x,
                        const float* __restrict__ W, const float* __restrict__ bias,
                        float* __restrict__ y){
  int b = blockIdx.x >> 4;
  int o = (blockIdx.x & 15) * 64 + (threadIdx.x >> 2);
  int q = threadIdx.x & 3;
  int k0 = q * 256;
  const float4* wr = (const float4*)(W + (size_t)o * 1024 + k0);
  const float4* xr = (const float4*)(x + b * 1024 + k0);
  float4 a = make_float4(0.f, 0.f, 0.f, 0.f);
  #pragma unroll 4
  for (int mI = 0; mI < 64; mI++){
    float4 wv = wr[mI], xv = xr[mI];
    a.x = fmaf(xv.x, wv.x, a.x);
    a.y = fmaf(xv.y, wv.y, a.y);
    a.z = fmaf(xv.z, wv.z, a.z);
    a.w = fmaf(xv.w, wv.w, a.w);
  }
  float r = a.x + a.y + a.z + a.w;
  r += __shfl_xor(r, 1, 64);
  r += __shfl_xor(r, 2, 64);
  if (q == 0) y[b * 1024 + o] = lrelu_(r + bias[o]);
}

// ---- MLP 3: 1024 -> 512 ----
__global__ __launch_bounds__(256) void k_mlp3(const float* __restrict__ x,
                        const float* __restrict__ W, const float* __restrict__ bias,
                        float* __restrict__ y){
  int b = blockIdx.x >> 3;
  int o = (blockIdx.x & 7) * 64 + (threadIdx.x >> 2);
  int q = threadIdx.x & 3;
  int k0 = q * 256;
  const float4* wr = (const float4*)(W + (size_t)o * 1024 + k0);
  const float4* xr = (const float4*)(x + b * 1024 + k0);
  float4 a = make_float4(0.f, 0.f, 0.f, 0.f);
  #pragma unroll 4
  for (int mI = 0; mI < 64; mI++){
    float4 wv = wr[mI], xv = xr[mI];
    a.x = fmaf(xv.x, wv.x, a.x);
    a.y = fmaf(xv.y, wv.y, a.y);
    a.z = fmaf(xv.z, wv.z, a.z);
    a.w = fmaf(xv.w, wv.w, a.w);
  }
  float r = a.x + a.y + a.z + a.w;
  r += __shfl_xor(r, 1, 64);
  r += __shfl_xor(r, 2, 64);
  if (q == 0) y[b * 512 + o] = lrelu_(r + bias[o]);
}

// ---- MLP out: 512 -> 2 ----
__global__ void k_mlp4(const float* __restrict__ f3, const float* __restrict__ Wo,
                       const float* __restrict__ bo, float* __restrict__ out){
  int tid = threadIdx.x;
  int g = tid >> 5, lane = tid & 31;
  int b = g >> 1, o = g & 1;
  const float4* xr = (const float4*)(f3 + b * 512);
  const float4* wr = (const float4*)(Wo + o * 512);
  float4 a = make_float4(0.f, 0.f, 0.f, 0.f);
  #pragma unroll
  for (int mI = 0; mI < 4; mI++){
    int k4 = lane + mI * 32;
    float4 xv = xr[k4], wv = wr[k4];
    a.x = fmaf(xv.x, wv.x, a.x);
    a.y = fmaf(xv.y, wv.y, a.y);
    a.z = fmaf(xv.z, wv.z, a.z);
    a.w = fmaf(xv.w, wv.w, a.w);
  }
  float r = a.x + a.y + a.z + a.w;
  for (int off = 16; off; off >>= 1) r += __shfl_xor(r, off, 64);
  if (lane == 0) out[b * 2 + o] = r + bo[o];
}

extern "C" void kernel_launch(void* const* d_in, const int* in_sizes, int n_in,
                              void* d_out, int out_size, void* d_ws, size_t ws_size,
                              hipStream_t stream) {
  const float* drug  = (const float*)d_in[0];
  const int*   natoms= (const int*)d_in[1];
  const int*   prot  = (const int*)d_in[2];
  const float* emb   = (const float*)d_in[3];
  const float* w1    = (const float*)d_in[4];
  const float* b1    = (const float*)d_in[5];
  const float* w2    = (const float*)d_in[6];
  const float* b2    = (const float*)d_in[7];
  const float* w3    = (const float*)d_in[8];
  const float* b3    = (const float*)d_in[9];
  const float* Wd    = (const float*)d_in[10];
  const float* bd    = (const float*)d_in[11];
  const float* Wp    = (const float*)d_in[12];
  const float* bp    = (const float*)d_in[13];
  const float* Watt  = (const float*)d_in[14];
  const float* batt  = (const float*)d_in[15];
  const float* W1    = (const float*)d_in[16];
  const float* bf1   = (const float*)d_in[17];
  const float* W2    = (const float*)d_in[18];
  const float* bf2   = (const float*)d_in[19];
  const float* W3    = (const float*)d_in[20];
  const float* bf3   = (const float*)d_in[21];
  const float* Wo    = (const float*)d_in[22];
  const float* bo    = (const float*)d_in[23];
  float* out = (float*)d_out;

  float* ws = (float*)d_ws;
  float* h1     = ws;                       // 160000 (dead after conv2g)
  float* cmeanT = ws;                       // 97280 (reuse of h1 region)
  float* f1     = ws + 97280;               // 4096
  float* f2     = ws + 101376;              // 4096
  float* f3     = ws + 105472;              // 2048
  float* h2     = ws + 160000;              // 317440 (post-relu)
  float* pconv  = ws + 477440;              // 627200 (post-relu)
  float* dattT  = ws + 1104640;             // 97280
  float* pattT  = ws + 1201920;             // 629760
  float* pmeanT = ws + 1831680;             // 629760
  unsigned* enc = (unsigned*)(ws + 2461440);// 1280 u32
  float* projG  = ws + 2461760;             // 4186

  k_proj  <<<17, 256, 0, stream>>>(emb, w1, projG);
  k_conv1 <<<BB * 80, 256, 0, stream>>>(prot, projG, b1, h1);
  k_conv2g<<<640, 128, 0, stream>>>(h1, w2, b2, h2);
  k_conv3g<<<1280, 128, 0, stream>>>(h2, w3, b3, pconv);
  k_datt  <<<80, 256, 0, stream>>>(drug, natoms, Wd, bd, dattT, enc);
  k_patt  <<<640, 128, 0, stream>>>(pconv, prot, Wp, bp, pattT);
  k_means <<<BB * NC3, 256, 0, stream>>>(dattT, pattT, cmeanT, pmeanT);
  k_atteC <<<80, 256, 0, stream>>>(cmeanT, Watt, batt, drug, enc);
  k_atteP <<<640, 128, 0, stream>>>(pmeanT, Watt, batt, pconv, enc);
  k_mlp1  <<<64, 256, 0, stream>>>(enc, W1, bf1, f1);
  k_mlp2  <<<64, 256, 0, stream>>>(f1, W2, bf2, f2);
  k_mlp3  <<<32, 256, 0, stream>>>(f2, W3, bf3, f3);
  k_mlp4  <<<1, 256, 0, stream>>>(f3, Wo, bo, out);
}

// Round 7
// 170.508 us; speedup vs baseline: 1.4371x; 1.1246x over previous
//
#include <hip/hip_runtime.h>
#include <math.h>

#define BB 4
#define DL 150
#define PL 1000
#define CD 64
#define NC1 40
#define NC2 80
#define NC3 160
#define L1O 997
#define L2O 990
#define L3O 979
#define L1P 1000
#define L2P 992
#define L3P 980
#define DLP 152
#define PLP 984
#define NINF (-1e30f)

__device__ __forceinline__ float relu_(float x){ return fmaxf(x, 0.f); }
__device__ __forceinline__ float lrelu_(float x){ return x > 0.f ? x : 0.01f * x; }

__device__ __forceinline__ unsigned fenc(float x){
  unsigned u = __float_as_uint(x);
  return (u & 0x80000000u) ? ~u : (u | 0x80000000u);
}
__device__ __forceinline__ float fdec(unsigned u){
  return __uint_as_float((u & 0x80000000u) ? (u & 0x7fffffffu) : ~u);
}
__device__ __forceinline__ float4 relu4_(float4 v){
  v.x = fmaxf(v.x, 0.f); v.y = fmaxf(v.y, 0.f);
  v.z = fmaxf(v.z, 0.f); v.w = fmaxf(v.w, 0.f);
  return v;
}

// ---- proj table ----
__global__ void k_proj(const float* __restrict__ emb, const float* __restrict__ w1,
                       float* __restrict__ projG){
  int e = blockIdx.x * 256 + threadIdx.x;
  if (e >= 26 * 160) return;
  int tok = e / 160, rem = e % 160, k = rem / 40, co = rem % 40;
  float a = 0.f;
  const float* er = emb + tok * CD;
  const float* wr = w1 + co * (CD * 4) + k;
  #pragma unroll 8
  for (int ci = 0; ci < CD; ci++) a = fmaf(er[ci], wr[ci * 4], a);
  projG[tok * 161 + k * 40 + co] = a;
}

// ---- conv1 apply (writes relu'd h1) ----
__global__ __launch_bounds__(256) void k_conv1(const int* __restrict__ prot,
                        const float* __restrict__ projG, const float* __restrict__ b1,
                        float* __restrict__ h1){
  __shared__ float sp[26 * 161];
  int b = blockIdx.x / 80;
  int t = (blockIdx.x % 80) * 256 + threadIdx.x;
  for (int k = threadIdx.x; k < 26 * 161; k += 256) sp[k] = projG[k];
  __syncthreads();
  int p = t & 1023, co2 = t >> 10;
  if (p >= L1O) return;
  const int* pr = prot + b * PL + p;
  int t0 = pr[0], t1 = pr[1], t2 = pr[2], t3 = pr[3];
  #pragma unroll
  for (int c = 0; c < 2; c++){
    int co = co2 * 2 + c;
    float a = b1[co] + sp[t0 * 161 + co] + sp[t1 * 161 + 40 + co]
            + sp[t2 * 161 + 80 + co] + sp[t3 * 161 + 120 + co];
    h1[(size_t)(b * NC1 + co) * L1P + p] = relu_(a);
  }
}

// ---- conv2: LDS whole-K tiled. grid 620 = b(4) x cog(5,16co) x pt(31,32p); 128 thr ----
#define C2XW 44
#define C2WP 324
__global__ __launch_bounds__(128) void k_c2(const float* __restrict__ h1,
                        const float* __restrict__ w, const float* __restrict__ bias,
                        float* __restrict__ h2){
  __shared__ float xs[NC1 * C2XW];            // 7.0 KB
  __shared__ float wl[16 * C2WP];             // 20.7 KB
  int blk = blockIdx.x;
  int pt = blk % 31; int t = blk / 31;
  int cog = t % 5; int b = t / 5;
  int co0 = cog * 16, pblk = pt * 32;
  int tid = threadIdx.x;
  const float* xb = h1 + (size_t)(b * NC1) * L1P + pblk;
  for (int i = tid; i < 440; i += 128){       // 40 rows x 11 f4
    int r = i / 11, c = i % 11;
    *(float4*)(&xs[r * C2XW + c * 4]) = *(const float4*)(xb + (size_t)r * L1P + c * 4);
  }
  for (int i = tid; i < 1280; i += 128){      // 16 co x 80 f4
    int cc = i / 80, c = i % 80;
    *(float4*)(&wl[cc * C2WP + c * 4]) =
        *(const float4*)(w + (size_t)(co0 + cc) * 320 + c * 4);
  }
  __syncthreads();
  int co_l = tid >> 3, pg = tid & 7, p0 = pg * 4;
  float acc[4] = {0,0,0,0};
  const float* wc = &wl[co_l * C2WP];
  #pragma unroll 2
  for (int ci = 0; ci < NC1; ci++){
    const float* xrow = &xs[ci * C2XW + p0];
    float xv[12];
    *(float4*)(&xv[0]) = *(const float4*)(xrow);
    *(float4*)(&xv[4]) = *(const float4*)(xrow + 4);
    *(float4*)(&xv[8]) = *(const float4*)(xrow + 8);
    float wk[8];
    *(float4*)(&wk[0]) = *(const float4*)(wc + ci * 8);
    *(float4*)(&wk[4]) = *(const float4*)(wc + ci * 8 + 4);
    #pragma unroll
    for (int k = 0; k < 8; k++){
      #pragma unroll
      for (int pp = 0; pp < 4; pp++)
        acc[pp] = fmaf(xv[pp + k], wk[k], acc[pp]);
    }
  }
  int co = co0 + co_l;
  float bv = bias[co];
  int pbase = pblk + p0;
  float* yr = h2 + (size_t)(b * NC2 + co) * L2P + pbase;
  if (pbase + 3 < L2O){
    float4 o; o.x = relu_(acc[0] + bv); o.y = relu_(acc[1] + bv);
    o.z = relu_(acc[2] + bv); o.w = relu_(acc[3] + bv);
    *(float4*)yr = o;
  } else {
    #pragma unroll
    for (int pp = 0; pp < 4; pp++)
      if (pbase + pp < L2O) yr[pp] = relu_(acc[pp] + bv);
  }
}

// ---- conv3: split-K(2), LDS tiled, dual outputs (no atomics). ----
// grid 1280 = b(4) x cog(10,16co) x pt(16,64p) x half(2,40ci); 256 thr
#define C3XW 76
#define C3WP 484
__global__ __launch_bounds__(256) void k_c3(const float* __restrict__ h2,
                        const float* __restrict__ w, const float* __restrict__ bias,
                        float* __restrict__ pA, float* __restrict__ pB){
  __shared__ float xs[40 * C3XW];             // 12.2 KB
  __shared__ float wl[16 * C3WP];             // 31.0 KB
  int blk = blockIdx.x;
  int half = blk & 1; int t = blk >> 1;
  int pt = t & 15; t >>= 4;
  int cog = t % 10; int b = t / 10;
  int co0 = cog * 16, pblk = pt * 64, ci0 = half * 40;
  int tid = threadIdx.x;
  const float* xb = h2 + (size_t)(b * NC2 + ci0) * L2P + pblk;
  for (int i = tid; i < 760; i += 256){       // 40 rows x 19 f4
    int r = i / 19, c = i % 19;
    *(float4*)(&xs[r * C3XW + c * 4]) = *(const float4*)(xb + (size_t)r * L2P + c * 4);
  }
  const float* wb = w + (size_t)co0 * 960 + ci0 * 12;
  for (int i = tid; i < 1920; i += 256){      // 16 co x 120 f4
    int cc = i / 120, c = i % 120;
    *(float4*)(&wl[cc * C3WP + c * 4]) =
        *(const float4*)(wb + (size_t)cc * 960 + c * 4);
  }
  __syncthreads();
  int co_l = tid >> 4, pg = tid & 15, p0 = pg * 4;
  float acc[4] = {0,0,0,0};
  const float* wc = &wl[co_l * C3WP];
  #pragma unroll 2
  for (int ci = 0; ci < 40; ci++){
    const float* xrow = &xs[ci * C3XW + p0];
    float xv[16];
    *(float4*)(&xv[0])  = *(const float4*)(xrow);
    *(float4*)(&xv[4])  = *(const float4*)(xrow + 4);
    *(float4*)(&xv[8])  = *(const float4*)(xrow + 8);
    *(float4*)(&xv[12]) = *(const float4*)(xrow + 12);
    float wk[12];
    *(float4*)(&wk[0]) = *(const float4*)(wc + ci * 12);
    *(float4*)(&wk[4]) = *(const float4*)(wc + ci * 12 + 4);
    *(float4*)(&wk[8]) = *(const float4*)(wc + ci * 12 + 8);
    #pragma unroll
    for (int k = 0; k < 12; k++){
      #pragma unroll
      for (int pp = 0; pp < 4; pp++)
        acc[pp] = fmaf(xv[pp + k], wk[k], acc[pp]);
    }
  }
  int co = co0 + co_l;
  float bv = (half == 0) ? bias[co] : 0.f;
  float* yr = (half == 0 ? pA : pB) + (size_t)(b * NC3 + co) * L3P;
  int pbase = pblk + p0;
  if (pbase + 3 < L3O){
    float4 o; o.x = acc[0] + bv; o.y = acc[1] + bv;
    o.z = acc[2] + bv; o.w = acc[3] + bv;
    *(float4*)(yr + pbase) = o;
  } else {
    #pragma unroll
    for (int pp = 0; pp < 4; pp++)
      if (pbase + pp < L3O) yr[pbase + pp] = acc[pp] + bv;
  }
}

// ---- drug attention: grid 160 = b(4) x cg(40,4c); + enc init ----
__global__ __launch_bounds__(256) void k_datt(const float* __restrict__ drug,
                        const int* __restrict__ natoms,
                        const float* __restrict__ Wd, const float* __restrict__ bd,
                        float* __restrict__ dattT, unsigned* __restrict__ enc){
  int blk = blockIdx.x;
  if (blk == 0){
    for (int k = threadIdx.x; k < 2 * BB * NC3; k += 256) enc[k] = 0u;
  }
  int b = blk / 40, c0 = (blk % 40) * 4;
  int i = threadIdx.x;
  if (i >= DL) return;
  const float4* xr = (const float4*)(drug + ((size_t)b * DL + i) * NC3);
  float4 a[4];
  #pragma unroll
  for (int cc = 0; cc < 4; cc++) a[cc] = make_float4(0.f, 0.f, 0.f, 0.f);
  for (int k4 = 0; k4 < 40; k4++){
    float4 xv = xr[k4];
    #pragma unroll
    for (int cc = 0; cc < 4; cc++){
      float4 wv = ((const float4*)(Wd + (size_t)(c0 + cc) * NC3))[k4];
      a[cc].x = fmaf(xv.x, wv.x, a[cc].x);
      a[cc].y = fmaf(xv.y, wv.y, a[cc].y);
      a[cc].z = fmaf(xv.z, wv.z, a[cc].z);
      a[cc].w = fmaf(xv.w, wv.w, a[cc].w);
    }
  }
  bool act = i < natoms[b];
  #pragma unroll
  for (int cc = 0; cc < 4; cc++){
    float r = act ? (a[cc].x + a[cc].y + a[cc].z + a[cc].w + bd[c0 + cc]) : 0.f;
    dattT[(size_t)(b * NC3 + c0 + cc) * DLP + i] = r;
  }
}

// ---- protein attention, tiled GEMM; X = relu(pA+pB) ----
__global__ __launch_bounds__(128) void k_patt(const float* __restrict__ pA,
                        const float* __restrict__ pB, const int* __restrict__ prot,
                        const float* __restrict__ Wp, const float* __restrict__ bp,
                        float* __restrict__ pattT){
  __shared__ float xs[160 * 68];
  __shared__ float wl[16 * 164];
  int blk = blockIdx.x;
  int jt = blk & 15; int t = blk >> 4;
  int cog = t % 10; int b = t / 10;
  int co0 = cog * 16, j0t = jt * 64;
  int tid = threadIdx.x;
  const float* xbA = pA + (size_t)(b * NC3) * L3P + j0t;
  const float* xbB = pB + (size_t)(b * NC3) * L3P + j0t;
  for (int i = tid; i < 2720; i += 128){
    int r = i / 17, c = i % 17;
    float4 vA = *(const float4*)(xbA + (size_t)r * L3P + c * 4);
    float4 vB = *(const float4*)(xbB + (size_t)r * L3P + c * 4);
    float4 v; v.x = vA.x + vB.x; v.y = vA.y + vB.y;
    v.z = vA.z + vB.z; v.w = vA.w + vB.w;
    *(float4*)(&xs[r * 68 + c * 4]) = relu4_(v);
  }
  for (int i = tid; i < 640; i += 128){
    int cc = i / 40, c = i % 40;
    *(float4*)(&wl[cc * 164 + c * 4]) =
        *(const float4*)(Wp + (size_t)(co0 + cc) * NC3 + c * 4);
  }
  __syncthreads();
  int cp = tid >> 4, jg = tid & 15;
  int j0 = jg * 4;
  float acc0[4] = {0,0,0,0}, acc1[4] = {0,0,0,0};
  const float* xcol = xs + j0;
  const float* w0r = wl + (cp * 2) * 164;
  const float* w1r = wl + (cp * 2 + 1) * 164;
  #pragma unroll 2
  for (int k4 = 0; k4 < 40; k4++){
    float4 wa = *(const float4*)(w0r + k4 * 4);
    float4 wb = *(const float4*)(w1r + k4 * 4);
    float4 x0 = *(const float4*)(xcol + (k4 * 4 + 0) * 68);
    float4 x1 = *(const float4*)(xcol + (k4 * 4 + 1) * 68);
    float4 x2 = *(const float4*)(xcol + (k4 * 4 + 2) * 68);
    float4 x3 = *(const float4*)(xcol + (k4 * 4 + 3) * 68);
    acc0[0] = fmaf(x0.x, wa.x, fmaf(x1.x, wa.y, fmaf(x2.x, wa.z, fmaf(x3.x, wa.w, acc0[0]))));
    acc0[1] = fmaf(x0.y, wa.x, fmaf(x1.y, wa.y, fmaf(x2.y, wa.z, fmaf(x3.y, wa.w, acc0[1]))));
    acc0[2] = fmaf(x0.z, wa.x, fmaf(x1.z, wa.y, fmaf(x2.z, wa.z, fmaf(x3.z, wa.w, acc0[2]))));
    acc0[3] = fmaf(x0.w, wa.x, fmaf(x1.w, wa.y, fmaf(x2.w, wa.z, fmaf(x3.w, wa.w, acc0[3]))));
    acc1[0] = fmaf(x0.x, wb.x, fmaf(x1.x, wb.y, fmaf(x2.x, wb.z, fmaf(x3.x, wb.w, acc1[0]))));
    acc1[1] = fmaf(x0.y, wb.x, fmaf(x1.y, wb.y, fmaf(x2.y, wb.z, fmaf(x3.y, wb.w, acc1[1]))));
    acc1[2] = fmaf(x0.z, wb.x, fmaf(x1.z, wb.y, fmaf(x2.z, wb.z, fmaf(x3.z, wb.w, acc1[2]))));
    acc1[3] = fmaf(x0.w, wb.x, fmaf(x1.w, wb.y, fmaf(x2.w, wb.z, fmaf(x3.w, wb.w, acc1[3]))));
  }
  int coA = co0 + cp * 2, coB = coA + 1;
  float bA = bp[coA], bB = bp[coB];
  int jb = j0t + j0;
  const int* pr = prot + b * PL;
  #pragma unroll
  for (int q = 0; q < 4; q++){
    int j = jb + q;
    if (j < L3O){
      bool act = pr[j] > 0;
      pattT[(size_t)(b * NC3 + coA) * PLP + j] = act ? (acc0[q] + bA) : 0.f;
      pattT[(size_t)(b * NC3 + coB) * PLP + j] = act ? (acc1[q] + bB) : 0.f;
    }
  }
}

// ---- means of relu(da_i + pa_j): block=(b,c) ----
__global__ __launch_bounds__(256) void k_means(const float* __restrict__ dattT,
                        const float* __restrict__ pattT,
                        float* __restrict__ cmeanT, float* __restrict__ pmeanT){
  __shared__ float4 sda4[DLP / 4];
  __shared__ float4 spa4[PLP / 4];
  float* sda = (float*)sda4;
  float* spa = (float*)spa4;
  int b = blockIdx.x / NC3, c = blockIdx.x % NC3;
  int tid = threadIdx.x;
  const float4* dr = (const float4*)(dattT + (size_t)(b * NC3 + c) * DLP);
  const float4* pr = (const float4*)(pattT + (size_t)(b * NC3 + c) * PLP);
  if (tid < DLP / 4) sda4[tid] = dr[tid];
  if (tid < PLP / 4) spa4[tid] = pr[tid];
  __syncthreads();
  if (tid < DL){
    float v = sda[tid];
    float s0 = 0.f, s1 = 0.f, s2 = 0.f, s3 = 0.f;
    for (int j4 = 0; j4 < 244; j4++){
      float4 p = spa4[j4];
      s0 += relu_(v + p.x); s1 += relu_(v + p.y);
      s2 += relu_(v + p.z); s3 += relu_(v + p.w);
    }
    s0 += relu_(v + spa[976]) + relu_(v + spa[977]) + relu_(v + spa[978]);
    cmeanT[(size_t)(b * NC3 + c) * DLP + tid] = (s0 + s1 + s2 + s3) * (1.f / L3O);
  }
  for (int j = tid; j < L3O; j += 256){
    float v = spa[j];
    float s0 = 0.f, s1 = 0.f, s2 = 0.f, s3 = 0.f;
    for (int i4 = 0; i4 < 37; i4++){
      float4 d = sda4[i4];
      s0 += relu_(v + d.x); s1 += relu_(v + d.y);
      s2 += relu_(v + d.z); s3 += relu_(v + d.w);
    }
    s0 += relu_(v + sda[148]) + relu_(v + sda[149]);
    pmeanT[(size_t)(b * NC3 + c) * PLP + j] = (s0 + s1 + s2 + s3) * (1.f / DL);
  }
}

// ---- compound gate + max-pool: grid 160 = b(4) x cg(40,4c) ----
__global__ __launch_bounds__(256) void k_atteC(const float* __restrict__ cmeanT,
                        const float* __restrict__ Watt, const float* __restrict__ batt,
                        const float* __restrict__ drug, unsigned* __restrict__ enc){
  __shared__ float sred[4][4];
  int blk = blockIdx.x;
  int b = blk / 40, c0 = (blk % 40) * 4;
  float m[4];
  #pragma unroll
  for (int cc = 0; cc < 4; cc++) m[cc] = NINF;
  int i = threadIdx.x;
  if (i < DL){
    float acc[4];
    #pragma unroll
    for (int cc = 0; cc < 4; cc++) acc[cc] = batt[c0 + cc];
    const float* xc = cmeanT + (size_t)b * NC3 * DLP + i;
    const float* wr = Watt + (size_t)c0 * NC3;
    for (int cb = 0; cb < NC3; cb += 32){
      float xv[32];
      #pragma unroll
      for (int u = 0; u < 32; u++) xv[u] = xc[(size_t)(cb + u) * DLP];
      #pragma unroll
      for (int u = 0; u < 32; u++){
        #pragma unroll
        for (int cc = 0; cc < 4; cc++)
          acc[cc] = fmaf(xv[u], wr[(size_t)cc * NC3 + cb + u], acc[cc]);
      }
    }
    const float* gr = drug + ((size_t)b * DL + i) * NC3 + c0;
    #pragma unroll
    for (int cc = 0; cc < 4; cc++){
      float atte = 1.f / (1.f + expf(-acc[cc]));
      m[cc] = gr[cc] * (0.5f + atte);
    }
  }
  int wave = threadIdx.x >> 6, lane = threadIdx.x & 63;
  #pragma unroll
  for (int cc = 0; cc < 4; cc++){
    float v = m[cc];
    for (int off = 1; off < 64; off <<= 1) v = fmaxf(v, __shfl_xor(v, off, 64));
    if (lane == 0) sred[wave][cc] = v;
  }
  __syncthreads();
  if (threadIdx.x < 4){
    float v = fmaxf(fmaxf(sred[0][threadIdx.x], sred[1][threadIdx.x]),
                    fmaxf(sred[2][threadIdx.x], sred[3][threadIdx.x]));
    atomicMax(&enc[b * NC3 + c0 + threadIdx.x], fenc(v));
  }
}

// ---- protein gate + max-pool, tiled; gates pconv = relu(pA+pB) ----
__global__ __launch_bounds__(128) void k_atteP(const float* __restrict__ pmeanT,
                        const float* __restrict__ Watt, const float* __restrict__ batt,
                        const float* __restrict__ pA, const float* __restrict__ pB,
                        unsigned* __restrict__ enc){
  __shared__ float xs[160 * 68];
  __shared__ float wl[16 * 164];
  int blk = blockIdx.x;
  int jt = blk & 15; int t = blk >> 4;
  int cog = t % 10; int b = t / 10;
  int co0 = cog * 16, j0t = jt * 64;
  int tid = threadIdx.x;
  const float* xb = pmeanT + (size_t)(b * NC3) * PLP + j0t;
  for (int i = tid; i < 2720; i += 128){
    int r = i / 17, c = i % 17;
    *(float4*)(&xs[r * 68 + c * 4]) = *(const float4*)(xb + (size_t)r * PLP + c * 4);
  }
  for (int i = tid; i < 640; i += 128){
    int cc = i / 40, c = i % 40;
    *(float4*)(&wl[cc * 164 + c * 4]) =
        *(const float4*)(Watt + (size_t)(co0 + cc) * NC3 + c * 4);
  }
  __syncthreads();
  int cp = tid >> 4, jg = tid & 15;
  int j0 = jg * 4;
  float acc0[4] = {0,0,0,0}, acc1[4] = {0,0,0,0};
  const float* xcol = xs + j0;
  const float* w0r = wl + (cp * 2) * 164;
  const float* w1r = wl + (cp * 2 + 1) * 164;
  #pragma unroll 2
  for (int k4 = 0; k4 < 40; k4++){
    float4 wa = *(const float4*)(w0r + k4 * 4);
    float4 wb = *(const float4*)(w1r + k4 * 4);
    float4 x0 = *(const float4*)(xcol + (k4 * 4 + 0) * 68);
    float4 x1 = *(const float4*)(xcol + (k4 * 4 + 1) * 68);
    float4 x2 = *(const float4*)(xcol + (k4 * 4 + 2) * 68);
    float4 x3 = *(const float4*)(xcol + (k4 * 4 + 3) * 68);
    acc0[0] = fmaf(x0.x, wa.x, fmaf(x1.x, wa.y, fmaf(x2.x, wa.z, fmaf(x3.x, wa.w, acc0[0]))));
    acc0[1] = fmaf(x0.y, wa.x, fmaf(x1.y, wa.y, fmaf(x2.y, wa.z, fmaf(x3.y, wa.w, acc0[1]))));
    acc0[2] = fmaf(x0.z, wa.x, fmaf(x1.z, wa.y, fmaf(x2.z, wa.z, fmaf(x3.z, wa.w, acc0[2]))));
    acc0[3] = fmaf(x0.w, wa.x, fmaf(x1.w, wa.y, fmaf(x2.w, wa.z, fmaf(x3.w, wa.w, acc0[3]))));
    acc1[0] = fmaf(x0.x, wb.x, fmaf(x1.x, wb.y, fmaf(x2.x, wb.z, fmaf(x3.x, wb.w, acc1[0]))));
    acc1[1] = fmaf(x0.y, wb.x, fmaf(x1.y, wb.y, fmaf(x2.y, wb.z, fmaf(x3.y, wb.w, acc1[1]))));
    acc1[2] = fmaf(x0.z, wb.x, fmaf(x1.z, wb.y, fmaf(x2.z, wb.z, fmaf(x3.z, wb.w, acc1[2]))));
    acc1[3] = fmaf(x0.w, wb.x, fmaf(x1.w, wb.y, fmaf(x2.w, wb.z, fmaf(x3.w, wb.w, acc1[3]))));
  }
  int coA = co0 + cp * 2, coB = coA + 1;
  float bA = batt[coA], bB = batt[coB];
  int jb = j0t + j0;
  float mA = NINF, mB = NINF;
  if (jb < L3P){
    const float* rA0 = pA + (size_t)(b * NC3 + coA) * L3P + jb;
    const float* rB0 = pB + (size_t)(b * NC3 + coA) * L3P + jb;
    const float* rA1 = pA + (size_t)(b * NC3 + coB) * L3P + jb;
    const float* rB1 = pB + (size_t)(b * NC3 + coB) * L3P + jb;
    float4 a0 = *(const float4*)rA0, b0 = *(const float4*)rB0;
    float4 a1 = *(const float4*)rA1, b1v = *(const float4*)rB1;
    float pAr[4] = {a0.x + b0.x, a0.y + b0.y, a0.z + b0.z, a0.w + b0.w};
    float pBr[4] = {a1.x + b1v.x, a1.y + b1v.y, a1.z + b1v.z, a1.w + b1v.w};
    #pragma unroll
    for (int q = 0; q < 4; q++){
      int j = jb + q;
      if (j < L3O){
        float gA = 1.f / (1.f + expf(-(acc0[q] + bA)));
        float gB = 1.f / (1.f + expf(-(acc1[q] + bB)));
        mA = fmaxf(mA, relu_(pAr[q]) * (0.5f + gA));
        mB = fmaxf(mB, relu_(pBr[q]) * (0.5f + gB));
      }
    }
  }
  #pragma unroll
  for (int off = 1; off < 16; off <<= 1){
    mA = fmaxf(mA, __shfl_xor(mA, off, 64));
    mB = fmaxf(mB, __shfl_xor(mB, off, 64));
  }
  if (jg == 0){
    atomicMax(&enc[BB * NC3 + b * NC3 + coA], fenc(mA));
    atomicMax(&enc[BB * NC3 + b * NC3 + coB], fenc(mB));
  }
}

// ---- MLP 1: 320 -> 1024; grid 256 = b(4) x og(64,16o); 16-way k-split ----
__global__ __launch_bounds__(256) void k_mlp1(const unsigned* __restrict__ enc,
                        const float* __restrict__ W1, const float* __restrict__ bf1,
                        float* __restrict__ f1){
  int b = blockIdx.x >> 6, og = blockIdx.x & 63;
  int o = og * 16 + (threadIdx.x >> 4);
  int q = threadIdx.x & 15;
  const float4* wr = (const float4*)(W1 + (size_t)o * 320);
  float4 a = make_float4(0.f, 0.f, 0.f, 0.f);
  #pragma unroll
  for (int mi = 0; mi < 5; mi++){
    int k4 = q + mi * 16;                       // f4 index; k = k4*4
    int k = k4 * 4;
    const unsigned* e = (k < 160) ? (enc + b * NC3 + k)
                                  : (enc + BB * NC3 + b * NC3 + (k - 160));
    float4 wv = wr[k4];
    a.x = fmaf(fdec(e[0]), wv.x, a.x);
    a.y = fmaf(fdec(e[1]), wv.y, a.y);
    a.z = fmaf(fdec(e[2]), wv.z, a.z);
    a.w = fmaf(fdec(e[3]), wv.w, a.w);
  }
  float r = a.x + a.y + a.z + a.w;
  r += __shfl_xor(r, 1, 64); r += __shfl_xor(r, 2, 64);
  r += __shfl_xor(r, 4, 64); r += __shfl_xor(r, 8, 64);
  if (q == 0) f1[b * 1024 + o] = lrelu_(r + bf1[o]);
}

// ---- MLP 2: 1024 -> 1024; grid 256 ----
__global__ __launch_bounds__(256) void k_mlp2(const float* __restrict__ x,
                        const float* __restrict__ W, const float* __restrict__ bias,
                        float* __restrict__ y){
  int b = blockIdx.x >> 6, og = blockIdx.x & 63;
  int o = og * 16 + (threadIdx.x >> 4);
  int q = threadIdx.x & 15;
  const float4* wr = (const float4*)(W + (size_t)o * 1024);
  const float4* xr = (const float4*)(x + b * 1024);
  float4 a = make_float4(0.f, 0.f, 0.f, 0.f);
  #pragma unroll
  for (int mi = 0; mi < 16; mi++){
    int k4 = q + mi * 16;
    float4 wv = wr[k4], xv = xr[k4];
    a.x = fmaf(xv.x, wv.x, a.x);
    a.y = fmaf(xv.y, wv.y, a.y);
    a.z = fmaf(xv.z, wv.z, a.z);
    a.w = fmaf(xv.w, wv.w, a.w);
  }
  float r = a.x + a.y + a.z + a.w;
  r += __shfl_xor(r, 1, 64); r += __shfl_xor(r, 2, 64);
  r += __shfl_xor(r, 4, 64); r += __shfl_xor(r, 8, 64);
  if (q == 0) y[b * 1024 + o] = lrelu_(r + bias[o]);
}

// ---- MLP 3: 1024 -> 512; grid 128 ----
__global__ __launch_bounds__(256) void k_mlp3(const float* __restrict__ x,
                        const float* __restrict__ W, const float* __restrict__ bias,
                        float* __restrict__ y){
  int b = blockIdx.x >> 5, og = blockIdx.x & 31;
  int o = og * 16 + (threadIdx.x >> 4);
  int q = threadIdx.x & 15;
  const float4* wr = (const float4*)(W + (size_t)o * 1024);
  const float4* xr = (const float4*)(x + b * 1024);
  float4 a = make_float4(0.f, 0.f, 0.f, 0.f);
  #pragma unroll
  for (int mi = 0; mi < 16; mi++){
    int k4 = q + mi * 16;
    float4 wv = wr[k4], xv = xr[k4];
    a.x = fmaf(xv.x, wv.x, a.x);
    a.y = fmaf(xv.y, wv.y, a.y);
    a.z = fmaf(xv.z, wv.z, a.z);
    a.w = fmaf(xv.w, wv.w, a.w);
  }
  float r = a.x + a.y + a.z + a.w;
  r += __shfl_xor(r, 1, 64); r += __shfl_xor(r, 2, 64);
  r += __shfl_xor(r, 4, 64); r += __shfl_xor(r, 8, 64);
  if (q == 0) y[b * 512 + o] = lrelu_(r + bias[o]);
}

// ---- MLP out: 512 -> 2 ----
__global__ void k_mlp4(const float* __restrict__ f3, const float* __restrict__ Wo,
                       const float* __restrict__ bo, float* __restrict__ out){
  int tid = threadIdx.x;
  int g = tid >> 5, lane = tid & 31;
  int b = g >> 1, o = g & 1;
  const float4* xr = (const float4*)(f3 + b * 512);
  const float4* wr = (const float4*)(Wo + o * 512);
  float4 a = make_float4(0.f, 0.f, 0.f, 0.f);
  #pragma unroll
  for (int mI = 0; mI < 4; mI++){
    int k4 = lane + mI * 32;
    float4 xv = xr[k4], wv = wr[k4];
    a.x = fmaf(xv.x, wv.x, a.x);
    a.y = fmaf(xv.y, wv.y, a.y);
    a.z = fmaf(xv.z, wv.z, a.z);
    a.w = fmaf(xv.w, wv.w, a.w);
  }
  float r = a.x + a.y + a.z + a.w;
  for (int off = 16; off; off >>= 1) r += __shfl_xor(r, off, 64);
  if (lane == 0) out[b * 2 + o] = r + bo[o];
}

extern "C" void kernel_launch(void* const* d_in, const int* in_sizes, int n_in,
                              void* d_out, int out_size, void* d_ws, size_t ws_size,
                              hipStream_t stream) {
  const float* drug  = (const float*)d_in[0];
  const int*   natoms= (const int*)d_in[1];
  const int*   prot  = (const int*)d_in[2];
  const float* emb   = (const float*)d_in[3];
  const float* w1    = (const float*)d_in[4];
  const float* b1    = (const float*)d_in[5];
  const float* w2    = (const float*)d_in[6];
  const float* b2    = (const float*)d_in[7];
  const float* w3    = (const float*)d_in[8];
  const float* b3    = (const float*)d_in[9];
  const float* Wd    = (const float*)d_in[10];
  const float* bd    = (const float*)d_in[11];
  const float* Wp    = (const float*)d_in[12];
  const float* bp    = (const float*)d_in[13];
  const float* Watt  = (const float*)d_in[14];
  const float* batt  = (const float*)d_in[15];
  const float* W1    = (const float*)d_in[16];
  const float* bf1   = (const float*)d_in[17];
  const float* W2    = (const float*)d_in[18];
  const float* bf2   = (const float*)d_in[19];
  const float* W3    = (const float*)d_in[20];
  const float* bf3   = (const float*)d_in[21];
  const float* Wo    = (const float*)d_in[22];
  const float* bo    = (const float*)d_in[23];
  float* out = (float*)d_out;

  float* ws = (float*)d_ws;
  float* h1     = ws;                       // 160000 (dead after k_c2)
  float* cmeanT = ws;                       // 97280 (reuse of h1 region)
  float* f1     = ws + 97280;               // 4096
  float* f2     = ws + 101376;              // 4096
  float* f3     = ws + 105472;              // 2048
  float* h2     = ws + 160000;              // 317440 (post-relu)
  float* pconvA = ws + 477440;              // 627200 (pre-relu partial K-half 0)
  float* dattT  = ws + 1104640;             // 97280
  float* pattT  = ws + 1201920;             // 629760
  float* pmeanT = ws + 1831680;             // 629760
  unsigned* enc = (unsigned*)(ws + 2461440);// 1280 u32
  float* projG  = ws + 2461760;             // 4186
  float* pconvB = ws + 2466048;             // 627200 (pre-relu partial K-half 1)

  k_proj  <<<17, 256, 0, stream>>>(emb, w1, projG);
  k_conv1 <<<BB * 80, 256, 0, stream>>>(prot, projG, b1, h1);
  k_c2    <<<620, 128, 0, stream>>>(h1, w2, b2, h2);
  k_c3    <<<1280, 256, 0, stream>>>(h2, w3, b3, pconvA, pconvB);
  k_datt  <<<160, 256, 0, stream>>>(drug, natoms, Wd, bd, dattT, enc);
  k_patt  <<<640, 128, 0, stream>>>(pconvA, pconvB, prot, Wp, bp, pattT);
  k_means <<<BB * NC3, 256, 0, stream>>>(dattT, pattT, cmeanT, pmeanT);
  k_atteC <<<160, 256, 0, stream>>>(cmeanT, Watt, batt, drug, enc);
  k_atteP <<<640, 128, 0, stream>>>(pmeanT, Watt, batt, pconvA, pconvB, enc);
  k_mlp1  <<<256, 256, 0, stream>>>(enc, W1, bf1, f1);
  k_mlp2  <<<256, 256, 0, stream>>>(f1, W2, bf2, f2);
  k_mlp3  <<<128, 256, 0, stream>>>(f2, W3, bf3, f3);
  k_mlp4  <<<1, 256, 0, stream>>>(f3, Wo, bo, out);
}